// Round 3
// baseline (358.425 us; speedup 1.0000x reference)
//
#include <hip/hip_runtime.h>

// CRF forward: B=512, T=1024, N=64. fwd/bwd split, one wave per chain.
// Round 13: round-12 DPP partial-output structure + E PINNED IN REGISTERS.
// Round-12 post-mortem: VGPR_Count=56 < the 64 floats of per-lane E ->
// the compiler demoted E2 (remat from LDS or scratch spill), so every step
// paid a hidden 64-value E reload; dispatch time tied round 11 (~214us,
// ~1000 cyc/step) even though the issued work is ~82 VALU ops (~200 cyc).
// Fix: one-time E load -> asm-opaque pin ("+v") so it cannot be remat'd or
// sunk; budget is 512 VGPRs at launch_bounds(128,1), pressure ~130.
// Also: 8-step load lookahead (raw u loaded 8 ahead, exp'd 4 ahead) so the
// ~900cyc HBM latency hides under the now-short steps.
// Math (verified, absmax 0.0 in rounds 10/12): exp-domain recurrence
//   a'_j = (sum_i a_i E_ij) * w_j, exponent-only rescale every 4 steps,
//   out = ln2 * (off_f + off_b + log2(sum_i a_i b_i)).
// Per step: 15 xor-DPP row-gather, 32 v_pk_fma_f32 partials,
// permlane32-pair-sum + ds_swizzle xor16 reduce, 3 cndmask select.

typedef float f2 __attribute__((ext_vector_type(2)));

constexpr int Tt = 1024;
constexpr int Nn = 64;
constexpr int ES = 68;  // f32 row stride for E staging (one-time)
constexpr float LN2 = 0.69314718055994530942f;

template<int CTRL>
__device__ __forceinline__ float dppf(float x) {
    return __uint_as_float((unsigned)__builtin_amdgcn_update_dpp(
        0, (int)__float_as_uint(x), CTRL, 0xF, 0xF, false));
}

// lane L gets value of lane L^16 (within each 32-lane group).
__device__ __forceinline__ float swz16(float x) {
    return __uint_as_float((unsigned)__builtin_amdgcn_ds_swizzle(
        (int)__float_as_uint(x), 0x401F));
}

// Pair-sum across the 32-lane halves, order-robust (swap with copy, add
// both outputs). s_nop 1 guards the VALU-write -> cross-lane-read hazard.
__device__ __forceinline__ float xsum32(float x) {
    float a = x, b = x;
    asm("s_nop 1\n\tv_permlane32_swap_b32 %0, %1" : "+v"(a), "+v"(b));
    return a + b;
}

__global__ __launch_bounds__(128, 1) void crf_fwd(
    const float* __restrict__ unary,
    const int*   __restrict__ lengths,
    const float* __restrict__ trans,
    float*       __restrict__ out)
{
    const int b    = blockIdx.x;
    const int tid  = threadIdx.x;
    const int w    = tid >> 6;   // 0 = forward wave, 1 = backward wave
    const int lane = tid & 63;
    const int p    = lane & 15;
    const int r    = lane >> 4;

    __shared__ float Erow[Nn * ES];   // Erow[i*ES+j] = exp(trans[i][j])
    __shared__ float shb[Nn];         // beta at midpoint (combine)
    __shared__ int   sh_off_b;        // bwd exponent offset

    // One-time staging of E = exp(trans).
    #pragma unroll
    for (int c = 0; c < (Nn * Nn) / 128; ++c) {
        int idx = c * 128 + tid;
        Erow[(idx >> 6) * ES + (idx & 63)] = __expf(trans[idx]);
    }
    __syncthreads();

    // Per-lane E fragment, permuted to the DPP gather order.
    // m -> s_m: XOR of masks {1,2,7,8} selected by m's bits.
    // fwd: M[o][i] = E[i][o] (a' = E^T a); bwd: M[o][i] = E[o][i].
    f2 E2[4][8];
    #pragma unroll
    for (int g = 0; g < 4; ++g) {
        #pragma unroll
        for (int m = 0; m < 16; ++m) {
            int s = ((m & 1) ? 1 : 0) ^ ((m & 2) ? 2 : 0)
                  ^ ((m & 4) ? 7 : 0) ^ ((m & 8) ? 8 : 0);
            int i = 16 * r + (p ^ s);
            int o = p + 16 * g;
            E2[g][m >> 1][m & 1] =
                (w == 0) ? Erow[i * ES + o] : Erow[o * ES + i];
        }
    }
    // PIN: make every E2 value the output of an opaque asm so the compiler
    // can neither rematerialize the LDS loads inside the loop nor sink them.
    #pragma unroll
    for (int g = 0; g < 4; ++g)
        #pragma unroll
        for (int q = 0; q < 8; ++q)
            asm volatile("" : "+v"(E2[g][q]));

    int L = lengths[b];
    L = L < 1 ? 1 : (L > Tt ? Tt : L);
    const int m2 = (L - 1) >> 1;

    const float* ub = unary + (size_t)b * Tt * Nn;

    const int trips = (w == 0) ? m2 : (L - 1 - m2);
    const int tbase = (w == 0) ? 1 : (L - 1);
    const int dir   = (w == 0) ? 1 : -1;

    // Exp-domain state + exponent offset.
    float acc = (w == 0) ? __expf(ub[lane]) : 1.0f;
    int   off = 0;

    // 8-step lookahead: wq = exp'd w for steps s0..s0+3,
    //                   uq = raw u for steps s0+4..s0+7.
    const int smax = trips > 0 ? trips - 1 : 0;
    float wq[4], uq[4];
    #pragma unroll
    for (int k = 0; k < 4; ++k) {
        int sc = k < smax ? k : smax;
        wq[k] = __expf(ub[(tbase + dir * sc) * Nn + lane]);
    }
    #pragma unroll
    for (int k = 0; k < 4; ++k) {
        int sc = 4 + k < smax ? 4 + k : smax;
        uq[k] = ub[(tbase + dir * sc) * Nn + lane];
    }

    for (int s0 = 0; s0 < trips; s0 += 4) {
        // Issue raw loads 8 steps ahead; exp the 4-ahead batch. Both
        // off the dependent chain.
        float un[4], wn[4];
        #pragma unroll
        for (int k = 0; k < 4; ++k) {
            int sc = s0 + 8 + k;
            if (sc > smax) sc = smax;
            un[k] = ub[(tbase + dir * sc) * Nn + lane];
        }
        #pragma unroll
        for (int k = 0; k < 4; ++k) wn[k] = __expf(uq[k]);

        #pragma unroll
        for (int k = 0; k < 4; ++k) {
            if (s0 + k >= trips) break;  // wave-uniform

            // fwd: a' = (E^T a) * w   (w on output)
            // bwd: a' = E (w * a)     (w on input)
            float src = (w != 0) ? acc * wq[k] : acc;

            // DPP row-gather: gp[q] = (a at pos p^s_{2q}, a at pos p^s_{2q+1}).
            f2 gp[8];
            gp[0][0] = src;                    // s=0
            gp[0][1] = dppf<0xB1>(gp[0][0]);   // s=1  quad_perm [1,0,3,2]
            gp[1][0] = dppf<0x4E>(gp[0][0]);   // s=2  quad_perm [2,3,0,1]
            gp[1][1] = dppf<0x4E>(gp[0][1]);   // s=3
            gp[2][0] = dppf<0x141>(gp[0][0]);  // s=7  row_half_mirror
            gp[2][1] = dppf<0x141>(gp[0][1]);  // s=6
            gp[3][0] = dppf<0x141>(gp[1][0]);  // s=5
            gp[3][1] = dppf<0x141>(gp[1][1]);  // s=4
            gp[4][0] = dppf<0x128>(gp[0][0]);  // s=8  row_ror:8 (== xor8)
            gp[4][1] = dppf<0x128>(gp[0][1]);  // s=9
            gp[5][0] = dppf<0x128>(gp[1][0]);  // s=10
            gp[5][1] = dppf<0x128>(gp[1][1]);  // s=11
            gp[6][0] = dppf<0x128>(gp[2][0]);  // s=15
            gp[6][1] = dppf<0x128>(gp[2][1]);  // s=14
            gp[7][0] = dppf<0x128>(gp[3][0]);  // s=13
            gp[7][1] = dppf<0x128>(gp[3][1]);  // s=12

            // Partials: P[g] = sum over own row (2 pk_fma chains, depth 4).
            f2 aA[4], aB[4];
            #pragma unroll
            for (int g = 0; g < 4; ++g) {
                aA[g] = (f2){0.f, 0.f};
                aB[g] = (f2){0.f, 0.f};
                #pragma unroll
                for (int q = 0; q < 8; q += 2) {
                    aA[g] = gp[q]     * E2[g][q]     + aA[g];
                    aB[g] = gp[q + 1] * E2[g][q + 1] + aB[g];
                }
            }

            // Cross-row reduce: stride-32 (permlane pair-sum) then stride-16
            // (swizzle xor16). Result replicated over each 4-lane group.
            float s1[4];
            #pragma unroll
            for (int g = 0; g < 4; ++g) {
                f2 t = aA[g] + aB[g];
                s1[g] = xsum32(t[0] + t[1]);
            }
            float sw[4];
            #pragma unroll
            for (int g = 0; g < 4; ++g) sw[g] = swz16(s1[g]);

            float z0 = s1[0] + sw[0], z1 = s1[1] + sw[1];
            float z2 = s1[2] + sw[2], z3 = s1[3] + sw[3];
            // Keep the group with g == own row r (r bits: lane&16, lane&32).
            float zl = (lane & 16) ? z1 : z0;
            float zh = (lane & 16) ? z3 : z2;
            float z  = (lane & 32) ? zh : zl;

            acc = (w == 0) ? z * wq[k] : z;
        }

        // Exact exponent-only rescale (once per 4 steps; keeps fp32 in
        // range: worst drift 4 steps * ~14 bits + ~10 bits lane spread).
        {
            unsigned s0b = (unsigned)__builtin_amdgcn_readfirstlane(
                (int)__float_as_uint(acc));
            int e = (int)((s0b >> 23) & 0xFF) - 127;
            off += e;
            acc *= __uint_as_float((unsigned)(127 - e) << 23);
        }

        #pragma unroll
        for (int k = 0; k < 4; ++k) { wq[k] = wn[k]; uq[k] = un[k]; }
    }

    // Combine: out[b] = ln2 * (off_f + off_b + log2(sum_i a_i * b_i)).
    if (w == 1) {
        shb[lane] = acc;
        if (lane == 0) sh_off_b = off;
    }
    __syncthreads();
    if (w == 0) {
        float v = acc * shb[lane];
        float ssum = v;
        #pragma unroll
        for (int k = 32; k >= 1; k >>= 1)
            ssum += __shfl_xor(ssum, k, 64);
        if (lane == 0) {
            float l2 = __builtin_amdgcn_logf(ssum);  // v_log_f32 = log2
            out[b] = LN2 * ((float)(off + sh_off_b) + l2);
        }
    }
}

extern "C" void kernel_launch(void* const* d_in, const int* in_sizes, int n_in,
                              void* d_out, int out_size, void* d_ws, size_t ws_size,
                              hipStream_t stream) {
    const float* unary   = (const float*)d_in[0];
    const int*   lengths = (const int*)d_in[1];
    const float* trans   = (const float*)d_in[2];
    float*       out     = (float*)d_out;

    const int Bb = in_sizes[1];  // 512
    crf_fwd<<<Bb, 128, 0, stream>>>(unary, lengths, trans, out);
}